// Round 1
// baseline (464.291 us; speedup 1.0000x reference)
//
#include <hip/hip_runtime.h>

#define H 128
#define NGRAPHS 128
#define NADV 32

// ---------------------------------------------------------------- utilities

__global__ void zero_int(int* __restrict__ p, int n) {
    int i = blockIdx.x * blockDim.x + threadIdx.x;
    if (i < n) p[i] = 0;
}

// ---------------------------------------------------------------- CSR build

__global__ void count_deg(const int* __restrict__ ei, int* __restrict__ deg, int E) {
    int e = blockIdx.x * blockDim.x + threadIdx.x;
    if (e < E) atomicAdd(&deg[ei[E + e]], 1);   // dst = edge_index[1][e]
}

__device__ __forceinline__ int wave_incl_scan(int v) {
    int lane = threadIdx.x & 63;
#pragma unroll
    for (int off = 1; off < 64; off <<= 1) {
        int t = __shfl_up(v, off);
        if (lane >= off) v += t;
    }
    return v;
}

// inclusive scan over 256 threads (4 waves)
__device__ __forceinline__ int block_incl_scan_256(int v, int* wsum) {
    int incl = wave_incl_scan(v);
    int wid = threadIdx.x >> 6;
    if ((threadIdx.x & 63) == 63) wsum[wid] = incl;
    __syncthreads();
    int prefix = 0;
#pragma unroll
    for (int w = 0; w < 4; ++w)
        if (w < wid) prefix += wsum[w];
    return incl + prefix;
}

__global__ __launch_bounds__(256) void block_sums(const int* __restrict__ deg,
                                                  int* __restrict__ bsum, int n) {
    __shared__ int wsum[4];
    int i = blockIdx.x * 256 + threadIdx.x;
    int s = (i < n) ? deg[i] : 0;
#pragma unroll
    for (int off = 32; off > 0; off >>= 1) s += __shfl_down(s, off);
    if ((threadIdx.x & 63) == 0) wsum[threadIdx.x >> 6] = s;
    __syncthreads();
    if (threadIdx.x == 0) bsum[blockIdx.x] = wsum[0] + wsum[1] + wsum[2] + wsum[3];
}

__global__ __launch_bounds__(256) void scan_bsums(const int* __restrict__ bsum,
                                                  int* __restrict__ boff, int nb) {
    __shared__ int wsum[4];
    int v = (threadIdx.x < nb) ? bsum[threadIdx.x] : 0;
    int incl = block_incl_scan_256(v, wsum);
    if (threadIdx.x < nb) boff[threadIdx.x] = incl - v;  // exclusive
}

__global__ __launch_bounds__(256) void scan_final(const int* __restrict__ deg,
                                                  const int* __restrict__ boff,
                                                  int* __restrict__ offs, int n) {
    __shared__ int wsum[4];
    int i = blockIdx.x * 256 + threadIdx.x;
    int v = (i < n) ? deg[i] : 0;
    int incl = block_incl_scan_256(v, wsum);
    if (i < n) offs[i + 1] = boff[blockIdx.x] + incl;
    if (i == 0) offs[0] = 0;
}

__global__ void scatter_edges(const int* __restrict__ ei, const int* __restrict__ offs,
                              int* __restrict__ cursor, int* __restrict__ csr, int E) {
    int e = blockIdx.x * blockDim.x + threadIdx.x;
    if (e < E) {
        int dst = ei[E + e];
        int src = ei[e];
        int pos = offs[dst] + atomicAdd(&cursor[dst], 1);
        csr[pos] = src;
    }
}

// ------------------------------------------------------------- aggregation
// out[node] = in[node] + sum_{e in csr[node]} in[src[e]]
__global__ __launch_bounds__(128) void agg_kernel(const float* __restrict__ in,
                                                  float* __restrict__ out,
                                                  const int* __restrict__ offs,
                                                  const int* __restrict__ csr, int n) {
    int node = blockIdx.x;
    int c = threadIdx.x;
    float s = in[node * H + c];
    int beg = offs[node], end = offs[node + 1];
    for (int e = beg; e < end; ++e) {
        int src = csr[e];
        s += in[src * H + c];
    }
    out[node * H + c] = s;
}

// ------------------------------------------------------------------- GEMM
// out[r][c] = relu( sum_k in[r][k] * W[k][c] + b[c] ),  in: [n,128], W: [128,128]
constexpr int TILE_R = 64;
constexpr int KT = 16;
constexpr int AS_STRIDE = 68;  // pad: 2-way max bank aliasing (free), keeps 16B align

__global__ __launch_bounds__(256) void gemm128_bias_relu(const float* __restrict__ in,
                                                         const float* __restrict__ W,
                                                         const float* __restrict__ bias,
                                                         float* __restrict__ out, int n) {
    __shared__ float As[KT * AS_STRIDE];  // transposed: As[k][r]
    __shared__ float Ws[KT * H];          // Ws[k][c]
    int tid = threadIdx.x;
    int tx = tid & 31;   // col group: cols 4*tx .. 4*tx+3
    int ty = tid >> 5;   // row group: rows 8*ty .. 8*ty+7
    int row0 = blockIdx.x * TILE_R;

    float acc[8][4] = {};

    int ar = tid >> 2;         // 0..63 (row within tile for A staging)
    int ak = (tid & 3) * 4;    // 0,4,8,12 (k offset for A staging)

    for (int k0 = 0; k0 < H; k0 += KT) {
        // stage A (transposed)
        int gr = row0 + ar;
        float4 av = (gr < n) ? *(const float4*)&in[gr * H + k0 + ak]
                             : make_float4(0.f, 0.f, 0.f, 0.f);
        As[(ak + 0) * AS_STRIDE + ar] = av.x;
        As[(ak + 1) * AS_STRIDE + ar] = av.y;
        As[(ak + 2) * AS_STRIDE + ar] = av.z;
        As[(ak + 3) * AS_STRIDE + ar] = av.w;
        // stage W
#pragma unroll
        for (int q = 0; q < 2; ++q) {
            int idx = tid + q * 256;
            int wr = idx >> 5, wc = (idx & 31) * 4;
            *(float4*)&Ws[wr * H + wc] = *(const float4*)&W[(k0 + wr) * H + wc];
        }
        __syncthreads();
#pragma unroll
        for (int kk = 0; kk < KT; ++kk) {
            float4 a0 = *(float4*)&As[kk * AS_STRIDE + ty * 8];
            float4 a1 = *(float4*)&As[kk * AS_STRIDE + ty * 8 + 4];
            float4 b = *(float4*)&Ws[kk * H + tx * 4];
            float a[8] = {a0.x, a0.y, a0.z, a0.w, a1.x, a1.y, a1.z, a1.w};
            float bb[4] = {b.x, b.y, b.z, b.w};
#pragma unroll
            for (int i = 0; i < 8; ++i)
#pragma unroll
                for (int j = 0; j < 4; ++j) acc[i][j] += a[i] * bb[j];
        }
        __syncthreads();
    }

    float4 bv = *(const float4*)&bias[tx * 4];
#pragma unroll
    for (int i = 0; i < 8; ++i) {
        int r = row0 + ty * 8 + i;
        if (r < n) {
            float4 o;
            o.x = fmaxf(acc[i][0] + bv.x, 0.f);
            o.y = fmaxf(acc[i][1] + bv.y, 0.f);
            o.z = fmaxf(acc[i][2] + bv.z, 0.f);
            o.w = fmaxf(acc[i][3] + bv.w, 0.f);
            *(float4*)&out[r * H + tx * 4] = o;
        }
    }
}

// ------------------------------------------------------------------- pool

__global__ void find_starts(const int* __restrict__ batch, int* __restrict__ starts,
                            int n, int ngraphs) {
    int g = blockIdx.x * blockDim.x + threadIdx.x;
    if (g > ngraphs) return;
    int lo = 0, hi = n;
    while (lo < hi) {
        int mid = (lo + hi) >> 1;
        if (batch[mid] < g) lo = mid + 1;
        else hi = mid;
    }
    starts[g] = lo;
}

__global__ __launch_bounds__(128) void pool_kernel(const float* __restrict__ h,
                                                   const int* __restrict__ starts,
                                                   float* __restrict__ g) {
    int gi = blockIdx.x;
    int c = threadIdx.x;
    int beg = starts[gi], end = starts[gi + 1];
    float s = 0.f;
    for (int r = beg; r < end; ++r) s += h[r * H + c];
    float cnt = (float)(end - beg);
    g[gi * H + c] = s / fmaxf(cnt, 1.0f);
}

// ------------------------------------------------------------------- head

__global__ __launch_bounds__(128) void head_kernel(const float* __restrict__ g,
                                                   const float* __restrict__ wv1,
                                                   const float* __restrict__ bv1,
                                                   const float* __restrict__ wv2,
                                                   const float* __restrict__ bv2,
                                                   const float* __restrict__ wa1,
                                                   const float* __restrict__ ba1,
                                                   const float* __restrict__ wa2,
                                                   const float* __restrict__ ba2,
                                                   float* __restrict__ out) {
    __shared__ float row[H];
    __shared__ float hv[H];
    __shared__ float ha[H];
    __shared__ float adv[NADV];
    __shared__ float vred[2];
    int gi = blockIdx.x;
    int c = threadIdx.x;
    row[c] = g[gi * H + c];
    __syncthreads();
    float sv = bv1[c], sa = ba1[c];
    for (int k = 0; k < H; ++k) {
        float rk = row[k];
        sv += rk * wv1[k * H + c];
        sa += rk * wa1[k * H + c];
    }
    hv[c] = fmaxf(sv, 0.f);
    ha[c] = fmaxf(sa, 0.f);
    __syncthreads();
    // value = dot(hv, wv2) + bv2
    float p = hv[c] * wv2[c];
#pragma unroll
    for (int off = 32; off > 0; off >>= 1) p += __shfl_down(p, off);
    if ((c & 63) == 0) vred[c >> 6] = p;
    __syncthreads();
    float value = vred[0] + vred[1] + bv2[0];
    if (c < NADV) {
        float s = ba2[c];
        for (int k = 0; k < H; ++k) s += ha[k] * wa2[k * NADV + c];
        adv[c] = s;
    }
    __syncthreads();
    if (c < NADV) {
        float m = 0.f;
#pragma unroll
        for (int j = 0; j < NADV; ++j) m += adv[j];
        m *= (1.0f / NADV);
        out[gi * NADV + c] = value + adv[c] - m;
    }
}

// ----------------------------------------------------------------- launch

extern "C" void kernel_launch(void* const* d_in, const int* in_sizes, int n_in,
                              void* d_out, int out_size, void* d_ws, size_t ws_size,
                              hipStream_t stream) {
    const float* x = (const float*)d_in[0];
    const int* ei = (const int*)d_in[1];
    const int* batch = (const int*)d_in[2];
    const float* w11 = (const float*)d_in[3];
    const float* b11 = (const float*)d_in[4];
    const float* w12 = (const float*)d_in[5];
    const float* b12 = (const float*)d_in[6];
    const float* w21 = (const float*)d_in[7];
    const float* b21 = (const float*)d_in[8];
    const float* w22 = (const float*)d_in[9];
    const float* b22 = (const float*)d_in[10];
    const float* wv1 = (const float*)d_in[11];
    const float* bv1 = (const float*)d_in[12];
    const float* wv2 = (const float*)d_in[13];
    const float* bv2 = (const float*)d_in[14];
    const float* wa1 = (const float*)d_in[15];
    const float* ba1 = (const float*)d_in[16];
    const float* wa2 = (const float*)d_in[17];
    const float* ba2 = (const float*)d_in[18];

    int N = in_sizes[2];
    int E = in_sizes[1] / 2;
    float* out = (float*)d_out;

    char* ws = (char*)d_ws;
    size_t off = 0;
    auto take = [&](size_t bytes) {
        void* p = ws + off;
        off = (off + bytes + 255) & ~(size_t)255;
        return p;
    };
    float* bufA = (float*)take((size_t)N * H * 4);
    float* bufB = (float*)take((size_t)N * H * 4);
    int* deg = (int*)take((size_t)N * 4);        // also reused as scatter cursor
    int* offs = (int*)take((size_t)(N + 1) * 4);
    int* csr = (int*)take((size_t)E * 4);
    int* bsum = (int*)take(4096);
    int* boff = (int*)take(4096);
    float* g = (float*)take((size_t)NGRAPHS * H * 4);
    int* starts = (int*)take((size_t)(NGRAPHS + 1) * 4);

    int nb = (N + 255) / 256;      // 196 (must be <= 256 for single-block scan)
    int eb = (E + 255) / 256;
    int gemmb = (N + TILE_R - 1) / TILE_R;

    // CSR build
    hipLaunchKernelGGL(zero_int, dim3(nb), dim3(256), 0, stream, deg, N);
    hipLaunchKernelGGL(count_deg, dim3(eb), dim3(256), 0, stream, ei, deg, E);
    hipLaunchKernelGGL(block_sums, dim3(nb), dim3(256), 0, stream, deg, bsum, N);
    hipLaunchKernelGGL(scan_bsums, dim3(1), dim3(256), 0, stream, bsum, boff, nb);
    hipLaunchKernelGGL(scan_final, dim3(nb), dim3(256), 0, stream, deg, boff, offs, N);
    hipLaunchKernelGGL(zero_int, dim3(nb), dim3(256), 0, stream, deg, N);
    hipLaunchKernelGGL(scatter_edges, dim3(eb), dim3(256), 0, stream, ei, offs, deg, csr, E);

    // layer 1
    hipLaunchKernelGGL(agg_kernel, dim3(N), dim3(128), 0, stream, x, bufA, offs, csr, N);
    hipLaunchKernelGGL(gemm128_bias_relu, dim3(gemmb), dim3(256), 0, stream, bufA, w11, b11, bufB, N);
    hipLaunchKernelGGL(gemm128_bias_relu, dim3(gemmb), dim3(256), 0, stream, bufB, w12, b12, bufA, N);
    // layer 2
    hipLaunchKernelGGL(agg_kernel, dim3(N), dim3(128), 0, stream, bufA, bufB, offs, csr, N);
    hipLaunchKernelGGL(gemm128_bias_relu, dim3(gemmb), dim3(256), 0, stream, bufB, w21, b21, bufA, N);
    hipLaunchKernelGGL(gemm128_bias_relu, dim3(gemmb), dim3(256), 0, stream, bufA, w22, b22, bufB, N);

    // pool + heads
    hipLaunchKernelGGL(find_starts, dim3(1), dim3(256), 0, stream, batch, starts, N, NGRAPHS);
    hipLaunchKernelGGL(pool_kernel, dim3(NGRAPHS), dim3(128), 0, stream, bufB, starts, g);
    hipLaunchKernelGGL(head_kernel, dim3(NGRAPHS), dim3(128), 0, stream, g,
                       wv1, bv1, wv2, bv2, wa1, ba1, wa2, ba2, out);
}

// Round 2
// 395.002 us; speedup vs baseline: 1.1754x; 1.1754x over previous
//
#include <hip/hip_runtime.h>

#define H 128
#define NGRAPHS 128
#define NADV 32

// ---------------------------------------------------------------- utilities

__global__ void zero_int(int* __restrict__ p, int n) {
    int i = blockIdx.x * blockDim.x + threadIdx.x;
    if (i < n) p[i] = 0;
}

__global__ void zero_float(float* __restrict__ p, int n) {
    int i = blockIdx.x * blockDim.x + threadIdx.x;
    if (i < n) p[i] = 0.f;
}

// ---------------------------------------------------------------- CSR build

__global__ void count_deg(const int* __restrict__ ei, int* __restrict__ deg, int E) {
    int e = blockIdx.x * blockDim.x + threadIdx.x;
    if (e < E) atomicAdd(&deg[ei[E + e]], 1);   // dst = edge_index[1][e]
}

__device__ __forceinline__ int wave_incl_scan(int v) {
    int lane = threadIdx.x & 63;
#pragma unroll
    for (int off = 1; off < 64; off <<= 1) {
        int t = __shfl_up(v, off);
        if (lane >= off) v += t;
    }
    return v;
}

// inclusive scan over 256 threads (4 waves)
__device__ __forceinline__ int block_incl_scan_256(int v, int* wsum) {
    int incl = wave_incl_scan(v);
    int wid = threadIdx.x >> 6;
    if ((threadIdx.x & 63) == 63) wsum[wid] = incl;
    __syncthreads();
    int prefix = 0;
#pragma unroll
    for (int w = 0; w < 4; ++w)
        if (w < wid) prefix += wsum[w];
    return incl + prefix;
}

__global__ __launch_bounds__(256) void block_sums(const int* __restrict__ deg,
                                                  int* __restrict__ bsum, int n) {
    __shared__ int wsum[4];
    int i = blockIdx.x * 256 + threadIdx.x;
    int s = (i < n) ? deg[i] : 0;
#pragma unroll
    for (int off = 32; off > 0; off >>= 1) s += __shfl_down(s, off);
    if ((threadIdx.x & 63) == 0) wsum[threadIdx.x >> 6] = s;
    __syncthreads();
    if (threadIdx.x == 0) bsum[blockIdx.x] = wsum[0] + wsum[1] + wsum[2] + wsum[3];
}

__global__ __launch_bounds__(256) void scan_bsums(const int* __restrict__ bsum,
                                                  int* __restrict__ boff, int nb) {
    __shared__ int wsum[4];
    int v = (threadIdx.x < nb) ? bsum[threadIdx.x] : 0;
    int incl = block_incl_scan_256(v, wsum);
    if (threadIdx.x < nb) boff[threadIdx.x] = incl - v;  // exclusive
}

__global__ __launch_bounds__(256) void scan_final(const int* __restrict__ deg,
                                                  const int* __restrict__ boff,
                                                  int* __restrict__ offs, int n) {
    __shared__ int wsum[4];
    int i = blockIdx.x * 256 + threadIdx.x;
    int v = (i < n) ? deg[i] : 0;
    int incl = block_incl_scan_256(v, wsum);
    if (i < n) offs[i + 1] = boff[blockIdx.x] + incl;
    if (i == 0) offs[0] = 0;
}

__global__ void scatter_edges(const int* __restrict__ ei, const int* __restrict__ offs,
                              int* __restrict__ cursor, int* __restrict__ csr, int E) {
    int e = blockIdx.x * blockDim.x + threadIdx.x;
    if (e < E) {
        int dst = ei[E + e];
        int src = ei[e];
        int pos = offs[dst] + atomicAdd(&cursor[dst], 1);
        csr[pos] = src;
    }
}

// ------------------------------------------------------------- aggregation
// out[node] = in[node] + sum_{e in csr[node]} in[src[e]]
__global__ __launch_bounds__(128) void agg_kernel(const float* __restrict__ in,
                                                  float* __restrict__ out,
                                                  const int* __restrict__ offs,
                                                  const int* __restrict__ csr, int n) {
    int node = blockIdx.x;
    int c = threadIdx.x;
    float s = in[node * H + c];
    int beg = offs[node], end = offs[node + 1];
    for (int e = beg; e < end; ++e) {
        int src = csr[e];
        s += in[src * H + c];
    }
    out[node * H + c] = s;
}

// ------------------------------------------------------------------- GEMM
// out[r][c] = relu( sum_k in[r][k] * W[k][c] + b[c] ),  in: [n,128], W: [128,128]
constexpr int TILE_R = 64;
constexpr int KT = 16;
constexpr int AS_STRIDE = 68;  // pad: 2-way max bank aliasing (free), keeps 16B align

__global__ __launch_bounds__(256) void gemm128_bias_relu(const float* __restrict__ in,
                                                         const float* __restrict__ W,
                                                         const float* __restrict__ bias,
                                                         float* __restrict__ out, int n) {
    __shared__ float As[KT * AS_STRIDE];  // transposed: As[k][r]
    __shared__ float Ws[KT * H];          // Ws[k][c]
    int tid = threadIdx.x;
    int tx = tid & 31;   // col group: cols 4*tx .. 4*tx+3
    int ty = tid >> 5;   // row group: rows 8*ty .. 8*ty+7
    int row0 = blockIdx.x * TILE_R;

    float acc[8][4] = {};

    int ar = tid >> 2;         // 0..63 (row within tile for A staging)
    int ak = (tid & 3) * 4;    // 0,4,8,12 (k offset for A staging)

    for (int k0 = 0; k0 < H; k0 += KT) {
        // stage A (transposed)
        int gr = row0 + ar;
        float4 av = (gr < n) ? *(const float4*)&in[gr * H + k0 + ak]
                             : make_float4(0.f, 0.f, 0.f, 0.f);
        As[(ak + 0) * AS_STRIDE + ar] = av.x;
        As[(ak + 1) * AS_STRIDE + ar] = av.y;
        As[(ak + 2) * AS_STRIDE + ar] = av.z;
        As[(ak + 3) * AS_STRIDE + ar] = av.w;
        // stage W
#pragma unroll
        for (int q = 0; q < 2; ++q) {
            int idx = tid + q * 256;
            int wr = idx >> 5, wc = (idx & 31) * 4;
            *(float4*)&Ws[wr * H + wc] = *(const float4*)&W[(k0 + wr) * H + wc];
        }
        __syncthreads();
#pragma unroll
        for (int kk = 0; kk < KT; ++kk) {
            float4 a0 = *(float4*)&As[kk * AS_STRIDE + ty * 8];
            float4 a1 = *(float4*)&As[kk * AS_STRIDE + ty * 8 + 4];
            float4 b = *(float4*)&Ws[kk * H + tx * 4];
            float a[8] = {a0.x, a0.y, a0.z, a0.w, a1.x, a1.y, a1.z, a1.w};
            float bb[4] = {b.x, b.y, b.z, b.w};
#pragma unroll
            for (int i = 0; i < 8; ++i)
#pragma unroll
                for (int j = 0; j < 4; ++j) acc[i][j] += a[i] * bb[j];
        }
        __syncthreads();
    }

    float4 bv = *(const float4*)&bias[tx * 4];
#pragma unroll
    for (int i = 0; i < 8; ++i) {
        int r = row0 + ty * 8 + i;
        if (r < n) {
            float4 o;
            o.x = fmaxf(acc[i][0] + bv.x, 0.f);
            o.y = fmaxf(acc[i][1] + bv.y, 0.f);
            o.z = fmaxf(acc[i][2] + bv.z, 0.f);
            o.w = fmaxf(acc[i][3] + bv.w, 0.f);
            *(float4*)&out[r * H + tx * 4] = o;
        }
    }
}

// ------------------------------------------------------------------- pool
// Parallel segmented mean-pool: partial sums per 128-row slab, atomicAdd on
// graph-boundary flush. batch is sorted, so each slab spans ~1-2 graphs.

__global__ void find_starts(const int* __restrict__ batch, int* __restrict__ starts,
                            int n, int ngraphs) {
    int g = blockIdx.x * blockDim.x + threadIdx.x;
    if (g > ngraphs) return;
    int lo = 0, hi = n;
    while (lo < hi) {
        int mid = (lo + hi) >> 1;
        if (batch[mid] < g) lo = mid + 1;
        else hi = mid;
    }
    starts[g] = lo;
}

constexpr int POOL_ROWS = 128;

__global__ __launch_bounds__(128) void pool_partial(const float* __restrict__ h,
                                                    const int* __restrict__ batch,
                                                    float* __restrict__ sums, int n) {
    __shared__ int bseg[POOL_ROWS];
    int r0 = blockIdx.x * POOL_ROWS;
    int r1 = min(r0 + POOL_ROWS, n);
    int nrows = r1 - r0;
    int c = threadIdx.x;
    if (c < nrows) bseg[c] = batch[r0 + c];
    __syncthreads();
    if (nrows <= 0) return;
    int g = bseg[0];
    float s = 0.f;
    for (int i = 0; i < nrows; ++i) {
        int bg = bseg[i];
        if (bg != g) {
            atomicAdd(&sums[g * H + c], s);
            s = 0.f;
            g = bg;
        }
        s += h[(r0 + i) * H + c];
    }
    atomicAdd(&sums[g * H + c], s);
}

__global__ __launch_bounds__(128) void pool_finalize(const float* __restrict__ sums,
                                                     const int* __restrict__ starts,
                                                     float* __restrict__ g) {
    int gi = blockIdx.x;
    int c = threadIdx.x;
    float cnt = (float)(starts[gi + 1] - starts[gi]);
    g[gi * H + c] = sums[gi * H + c] / fmaxf(cnt, 1.0f);
}

// ------------------------------------------------------------------- head

__global__ __launch_bounds__(128) void head_kernel(const float* __restrict__ g,
                                                   const float* __restrict__ wv1,
                                                   const float* __restrict__ bv1,
                                                   const float* __restrict__ wv2,
                                                   const float* __restrict__ bv2,
                                                   const float* __restrict__ wa1,
                                                   const float* __restrict__ ba1,
                                                   const float* __restrict__ wa2,
                                                   const float* __restrict__ ba2,
                                                   float* __restrict__ out) {
    __shared__ float row[H];
    __shared__ float hv[H];
    __shared__ float ha[H];
    __shared__ float adv[NADV];
    __shared__ float vred[2];
    int gi = blockIdx.x;
    int c = threadIdx.x;
    row[c] = g[gi * H + c];
    __syncthreads();
    float sv = bv1[c], sa = ba1[c];
    for (int k = 0; k < H; ++k) {
        float rk = row[k];
        sv += rk * wv1[k * H + c];
        sa += rk * wa1[k * H + c];
    }
    hv[c] = fmaxf(sv, 0.f);
    ha[c] = fmaxf(sa, 0.f);
    __syncthreads();
    // value = dot(hv, wv2) + bv2
    float p = hv[c] * wv2[c];
#pragma unroll
    for (int off = 32; off > 0; off >>= 1) p += __shfl_down(p, off);
    if ((c & 63) == 0) vred[c >> 6] = p;
    __syncthreads();
    float value = vred[0] + vred[1] + bv2[0];
    if (c < NADV) {
        float s = ba2[c];
        for (int k = 0; k < H; ++k) s += ha[k] * wa2[k * NADV + c];
        adv[c] = s;
    }
    __syncthreads();
    if (c < NADV) {
        float m = 0.f;
#pragma unroll
        for (int j = 0; j < NADV; ++j) m += adv[j];
        m *= (1.0f / NADV);
        out[gi * NADV + c] = value + adv[c] - m;
    }
}

// ----------------------------------------------------------------- launch

extern "C" void kernel_launch(void* const* d_in, const int* in_sizes, int n_in,
                              void* d_out, int out_size, void* d_ws, size_t ws_size,
                              hipStream_t stream) {
    const float* x = (const float*)d_in[0];
    const int* ei = (const int*)d_in[1];
    const int* batch = (const int*)d_in[2];
    const float* w11 = (const float*)d_in[3];
    const float* b11 = (const float*)d_in[4];
    const float* w12 = (const float*)d_in[5];
    const float* b12 = (const float*)d_in[6];
    const float* w21 = (const float*)d_in[7];
    const float* b21 = (const float*)d_in[8];
    const float* w22 = (const float*)d_in[9];
    const float* b22 = (const float*)d_in[10];
    const float* wv1 = (const float*)d_in[11];
    const float* bv1 = (const float*)d_in[12];
    const float* wv2 = (const float*)d_in[13];
    const float* bv2 = (const float*)d_in[14];
    const float* wa1 = (const float*)d_in[15];
    const float* ba1 = (const float*)d_in[16];
    const float* wa2 = (const float*)d_in[17];
    const float* ba2 = (const float*)d_in[18];

    int N = in_sizes[2];
    int E = in_sizes[1] / 2;
    float* out = (float*)d_out;

    char* ws = (char*)d_ws;
    size_t off = 0;
    auto take = [&](size_t bytes) {
        void* p = ws + off;
        off = (off + bytes + 255) & ~(size_t)255;
        return p;
    };
    float* bufA = (float*)take((size_t)N * H * 4);
    float* bufB = (float*)take((size_t)N * H * 4);
    int* deg = (int*)take((size_t)N * 4);        // also reused as scatter cursor
    int* offs = (int*)take((size_t)(N + 1) * 4);
    int* csr = (int*)take((size_t)E * 4);
    int* bsum = (int*)take(4096);
    int* boff = (int*)take(4096);
    float* gsum = (float*)take((size_t)NGRAPHS * H * 4);
    float* g = (float*)take((size_t)NGRAPHS * H * 4);
    int* starts = (int*)take((size_t)(NGRAPHS + 1) * 4);

    int nb = (N + 255) / 256;      // 196 (must be <= 256 for single-block scan)
    int eb = (E + 255) / 256;
    int gemmb = (N + TILE_R - 1) / TILE_R;
    int poolb = (N + POOL_ROWS - 1) / POOL_ROWS;

    // CSR build
    hipLaunchKernelGGL(zero_int, dim3(nb), dim3(256), 0, stream, deg, N);
    hipLaunchKernelGGL(count_deg, dim3(eb), dim3(256), 0, stream, ei, deg, E);
    hipLaunchKernelGGL(block_sums, dim3(nb), dim3(256), 0, stream, deg, bsum, N);
    hipLaunchKernelGGL(scan_bsums, dim3(1), dim3(256), 0, stream, bsum, boff, nb);
    hipLaunchKernelGGL(scan_final, dim3(nb), dim3(256), 0, stream, deg, boff, offs, N);
    hipLaunchKernelGGL(zero_int, dim3(nb), dim3(256), 0, stream, deg, N);
    hipLaunchKernelGGL(scatter_edges, dim3(eb), dim3(256), 0, stream, ei, offs, deg, csr, E);

    // layer 1
    hipLaunchKernelGGL(agg_kernel, dim3(N), dim3(128), 0, stream, x, bufA, offs, csr, N);
    hipLaunchKernelGGL(gemm128_bias_relu, dim3(gemmb), dim3(256), 0, stream, bufA, w11, b11, bufB, N);
    hipLaunchKernelGGL(gemm128_bias_relu, dim3(gemmb), dim3(256), 0, stream, bufB, w12, b12, bufA, N);
    // layer 2
    hipLaunchKernelGGL(agg_kernel, dim3(N), dim3(128), 0, stream, bufA, bufB, offs, csr, N);
    hipLaunchKernelGGL(gemm128_bias_relu, dim3(gemmb), dim3(256), 0, stream, bufB, w21, b21, bufA, N);
    hipLaunchKernelGGL(gemm128_bias_relu, dim3(gemmb), dim3(256), 0, stream, bufA, w22, b22, bufB, N);

    // pool + heads
    hipLaunchKernelGGL(find_starts, dim3(1), dim3(256), 0, stream, batch, starts, N, NGRAPHS);
    hipLaunchKernelGGL(zero_float, dim3((NGRAPHS * H + 255) / 256), dim3(256), 0, stream,
                       gsum, NGRAPHS * H);
    hipLaunchKernelGGL(pool_partial, dim3(poolb), dim3(128), 0, stream, bufB, batch, gsum, N);
    hipLaunchKernelGGL(pool_finalize, dim3(NGRAPHS), dim3(128), 0, stream, gsum, starts, g);
    hipLaunchKernelGGL(head_kernel, dim3(NGRAPHS), dim3(128), 0, stream, g,
                       wv1, bv1, wv2, bv2, wa1, ba1, wa2, ba2, out);
}

// Round 3
// 352.246 us; speedup vs baseline: 1.3181x; 1.1214x over previous
//
#include <hip/hip_runtime.h>

#define H 128
#define NGRAPHS 128
#define NADV 32

// ---------------------------------------------------------------- utilities

__global__ void zero_int(int* __restrict__ p, int n) {
    int i = blockIdx.x * blockDim.x + threadIdx.x;
    if (i < n) p[i] = 0;
}

__global__ void zero_float(float* __restrict__ p, int n) {
    int i = blockIdx.x * blockDim.x + threadIdx.x;
    if (i < n) p[i] = 0.f;
}

// ---------------------------------------------------------------- CSR build

__global__ void count_deg(const int* __restrict__ ei, int* __restrict__ deg, int E) {
    int e = blockIdx.x * blockDim.x + threadIdx.x;
    if (e < E) atomicAdd(&deg[ei[E + e]], 1);   // dst = edge_index[1][e]
}

__device__ __forceinline__ int wave_incl_scan(int v) {
    int lane = threadIdx.x & 63;
#pragma unroll
    for (int off = 1; off < 64; off <<= 1) {
        int t = __shfl_up(v, off);
        if (lane >= off) v += t;
    }
    return v;
}

// inclusive scan over 256 threads (4 waves)
__device__ __forceinline__ int block_incl_scan_256(int v, int* wsum) {
    int incl = wave_incl_scan(v);
    int wid = threadIdx.x >> 6;
    if ((threadIdx.x & 63) == 63) wsum[wid] = incl;
    __syncthreads();
    int prefix = 0;
#pragma unroll
    for (int w = 0; w < 4; ++w)
        if (w < wid) prefix += wsum[w];
    return incl + prefix;
}

__global__ __launch_bounds__(256) void block_sums(const int* __restrict__ deg,
                                                  int* __restrict__ bsum, int n) {
    __shared__ int wsum[4];
    int i = blockIdx.x * 256 + threadIdx.x;
    int s = (i < n) ? deg[i] : 0;
#pragma unroll
    for (int off = 32; off > 0; off >>= 1) s += __shfl_down(s, off);
    if ((threadIdx.x & 63) == 0) wsum[threadIdx.x >> 6] = s;
    __syncthreads();
    if (threadIdx.x == 0) bsum[blockIdx.x] = wsum[0] + wsum[1] + wsum[2] + wsum[3];
}

__global__ __launch_bounds__(256) void scan_bsums(const int* __restrict__ bsum,
                                                  int* __restrict__ boff, int nb) {
    __shared__ int wsum[4];
    int v = (threadIdx.x < nb) ? bsum[threadIdx.x] : 0;
    int incl = block_incl_scan_256(v, wsum);
    if (threadIdx.x < nb) boff[threadIdx.x] = incl - v;  // exclusive
}

__global__ __launch_bounds__(256) void scan_final(const int* __restrict__ deg,
                                                  const int* __restrict__ boff,
                                                  int* __restrict__ offs, int n) {
    __shared__ int wsum[4];
    int i = blockIdx.x * 256 + threadIdx.x;
    int v = (i < n) ? deg[i] : 0;
    int incl = block_incl_scan_256(v, wsum);
    if (i < n) offs[i + 1] = boff[blockIdx.x] + incl;
    if (i == 0) offs[0] = 0;
}

__global__ void scatter_edges(const int* __restrict__ ei, const int* __restrict__ offs,
                              int* __restrict__ cursor, int* __restrict__ csr, int E) {
    int e = blockIdx.x * blockDim.x + threadIdx.x;
    if (e < E) {
        int dst = ei[E + e];
        int src = ei[e];
        int pos = offs[dst] + atomicAdd(&cursor[dst], 1);
        csr[pos] = src;
    }
}

// ------------------------------------------------------------- aggregation
// out[node] = in[node] + sum_{e in csr[node]} in[src[e]]
// v2: 8 nodes/block, 32 lanes per node row, float4 per lane. Indices are
// pre-loaded coalesced (one per lane) and broadcast via shfl so all gathers
// in a chunk are independent (no csr->gather dependent chain).
constexpr int AGG_NODES = 8;

__global__ __launch_bounds__(256) void agg_kernel2(const float* __restrict__ in,
                                                   float* __restrict__ out,
                                                   const int* __restrict__ offs,
                                                   const int* __restrict__ csr, int n) {
    int t = threadIdx.x;
    int lane = t & 31;                       // lane within node group
    int node = blockIdx.x * AGG_NODES + (t >> 5);
    if (node >= n) return;
    const float4* inv = (const float4*)in;
    int beg = offs[node], end = offs[node + 1];
    float4 acc = inv[(size_t)node * 32 + lane];   // self term
    for (int e0 = beg; e0 < end; e0 += 32) {
        int cnt = min(32, end - e0);
        int myidx = (lane < cnt) ? csr[e0 + lane] : 0;
        for (int j = 0; j < cnt; ++j) {
            int src = __shfl(myidx, j, 32);
            float4 v = inv[(size_t)src * 32 + lane];
            acc.x += v.x; acc.y += v.y; acc.z += v.z; acc.w += v.w;
        }
    }
    ((float4*)out)[(size_t)node * 32 + lane] = acc;
}

// ------------------------------------------------------------------- GEMM
// out[r][c] = relu( sum_k in[r][k] * W[k][c] + b[c] ),  in: [n,128], W: [128,128]
constexpr int TILE_R = 64;
constexpr int KT = 16;
constexpr int AS_STRIDE = 68;  // pad: 2-way max bank aliasing (free), keeps 16B align

__global__ __launch_bounds__(256) void gemm128_bias_relu(const float* __restrict__ in,
                                                         const float* __restrict__ W,
                                                         const float* __restrict__ bias,
                                                         float* __restrict__ out, int n) {
    __shared__ float As[KT * AS_STRIDE];  // transposed: As[k][r]
    __shared__ float Ws[KT * H];          // Ws[k][c]
    int tid = threadIdx.x;
    int tx = tid & 31;   // col group: cols 4*tx .. 4*tx+3
    int ty = tid >> 5;   // row group: rows 8*ty .. 8*ty+7
    int row0 = blockIdx.x * TILE_R;

    float acc[8][4] = {};

    int ar = tid >> 2;         // 0..63 (row within tile for A staging)
    int ak = (tid & 3) * 4;    // 0,4,8,12 (k offset for A staging)

    for (int k0 = 0; k0 < H; k0 += KT) {
        // stage A (transposed)
        int gr = row0 + ar;
        float4 av = (gr < n) ? *(const float4*)&in[gr * H + k0 + ak]
                             : make_float4(0.f, 0.f, 0.f, 0.f);
        As[(ak + 0) * AS_STRIDE + ar] = av.x;
        As[(ak + 1) * AS_STRIDE + ar] = av.y;
        As[(ak + 2) * AS_STRIDE + ar] = av.z;
        As[(ak + 3) * AS_STRIDE + ar] = av.w;
        // stage W
#pragma unroll
        for (int q = 0; q < 2; ++q) {
            int idx = tid + q * 256;
            int wr = idx >> 5, wc = (idx & 31) * 4;
            *(float4*)&Ws[wr * H + wc] = *(const float4*)&W[(k0 + wr) * H + wc];
        }
        __syncthreads();
#pragma unroll
        for (int kk = 0; kk < KT; ++kk) {
            float4 a0 = *(float4*)&As[kk * AS_STRIDE + ty * 8];
            float4 a1 = *(float4*)&As[kk * AS_STRIDE + ty * 8 + 4];
            float4 b = *(float4*)&Ws[kk * H + tx * 4];
            float a[8] = {a0.x, a0.y, a0.z, a0.w, a1.x, a1.y, a1.z, a1.w};
            float bb[4] = {b.x, b.y, b.z, b.w};
#pragma unroll
            for (int i = 0; i < 8; ++i)
#pragma unroll
                for (int j = 0; j < 4; ++j) acc[i][j] += a[i] * bb[j];
        }
        __syncthreads();
    }

    float4 bv = *(const float4*)&bias[tx * 4];
#pragma unroll
    for (int i = 0; i < 8; ++i) {
        int r = row0 + ty * 8 + i;
        if (r < n) {
            float4 o;
            o.x = fmaxf(acc[i][0] + bv.x, 0.f);
            o.y = fmaxf(acc[i][1] + bv.y, 0.f);
            o.z = fmaxf(acc[i][2] + bv.z, 0.f);
            o.w = fmaxf(acc[i][3] + bv.w, 0.f);
            *(float4*)&out[r * H + tx * 4] = o;
        }
    }
}

// ------------------------------------------------------------------- pool
// Parallel segmented mean-pool: partial sums per 128-row slab, atomicAdd on
// graph-boundary flush. batch is sorted, so each slab spans ~1-2 graphs.

__global__ void find_starts(const int* __restrict__ batch, int* __restrict__ starts,
                            int n, int ngraphs) {
    int g = blockIdx.x * blockDim.x + threadIdx.x;
    if (g > ngraphs) return;
    int lo = 0, hi = n;
    while (lo < hi) {
        int mid = (lo + hi) >> 1;
        if (batch[mid] < g) lo = mid + 1;
        else hi = mid;
    }
    starts[g] = lo;
}

constexpr int POOL_ROWS = 128;

__global__ __launch_bounds__(128) void pool_partial(const float* __restrict__ h,
                                                    const int* __restrict__ batch,
                                                    float* __restrict__ sums, int n) {
    __shared__ int bseg[POOL_ROWS];
    int r0 = blockIdx.x * POOL_ROWS;
    int r1 = min(r0 + POOL_ROWS, n);
    int nrows = r1 - r0;
    int c = threadIdx.x;
    if (c < nrows) bseg[c] = batch[r0 + c];
    __syncthreads();
    if (nrows <= 0) return;
    int g = bseg[0];
    float s = 0.f;
    for (int i = 0; i < nrows; ++i) {
        int bg = bseg[i];
        if (bg != g) {
            atomicAdd(&sums[g * H + c], s);
            s = 0.f;
            g = bg;
        }
        s += h[(r0 + i) * H + c];
    }
    atomicAdd(&sums[g * H + c], s);
}

__global__ __launch_bounds__(128) void pool_finalize(const float* __restrict__ sums,
                                                     const int* __restrict__ starts,
                                                     float* __restrict__ g) {
    int gi = blockIdx.x;
    int c = threadIdx.x;
    float cnt = (float)(starts[gi + 1] - starts[gi]);
    g[gi * H + c] = sums[gi * H + c] / fmaxf(cnt, 1.0f);
}

// ------------------------------------------------------------------- head

__global__ __launch_bounds__(128) void head_kernel(const float* __restrict__ g,
                                                   const float* __restrict__ wv1,
                                                   const float* __restrict__ bv1,
                                                   const float* __restrict__ wv2,
                                                   const float* __restrict__ bv2,
                                                   const float* __restrict__ wa1,
                                                   const float* __restrict__ ba1,
                                                   const float* __restrict__ wa2,
                                                   const float* __restrict__ ba2,
                                                   float* __restrict__ out) {
    __shared__ float row[H];
    __shared__ float hv[H];
    __shared__ float ha[H];
    __shared__ float adv[NADV];
    __shared__ float vred[2];
    int gi = blockIdx.x;
    int c = threadIdx.x;
    row[c] = g[gi * H + c];
    __syncthreads();
    float sv = bv1[c], sa = ba1[c];
    for (int k = 0; k < H; ++k) {
        float rk = row[k];
        sv += rk * wv1[k * H + c];
        sa += rk * wa1[k * H + c];
    }
    hv[c] = fmaxf(sv, 0.f);
    ha[c] = fmaxf(sa, 0.f);
    __syncthreads();
    // value = dot(hv, wv2) + bv2
    float p = hv[c] * wv2[c];
#pragma unroll
    for (int off = 32; off > 0; off >>= 1) p += __shfl_down(p, off);
    if ((c & 63) == 0) vred[c >> 6] = p;
    __syncthreads();
    float value = vred[0] + vred[1] + bv2[0];
    if (c < NADV) {
        float s = ba2[c];
        for (int k = 0; k < H; ++k) s += ha[k] * wa2[k * NADV + c];
        adv[c] = s;
    }
    __syncthreads();
    if (c < NADV) {
        float m = 0.f;
#pragma unroll
        for (int j = 0; j < NADV; ++j) m += adv[j];
        m *= (1.0f / NADV);
        out[gi * NADV + c] = value + adv[c] - m;
    }
}

// ----------------------------------------------------------------- launch

extern "C" void kernel_launch(void* const* d_in, const int* in_sizes, int n_in,
                              void* d_out, int out_size, void* d_ws, size_t ws_size,
                              hipStream_t stream) {
    const float* x = (const float*)d_in[0];
    const int* ei = (const int*)d_in[1];
    const int* batch = (const int*)d_in[2];
    const float* w11 = (const float*)d_in[3];
    const float* b11 = (const float*)d_in[4];
    const float* w12 = (const float*)d_in[5];
    const float* b12 = (const float*)d_in[6];
    const float* w21 = (const float*)d_in[7];
    const float* b21 = (const float*)d_in[8];
    const float* w22 = (const float*)d_in[9];
    const float* b22 = (const float*)d_in[10];
    const float* wv1 = (const float*)d_in[11];
    const float* bv1 = (const float*)d_in[12];
    const float* wv2 = (const float*)d_in[13];
    const float* bv2 = (const float*)d_in[14];
    const float* wa1 = (const float*)d_in[15];
    const float* ba1 = (const float*)d_in[16];
    const float* wa2 = (const float*)d_in[17];
    const float* ba2 = (const float*)d_in[18];

    int N = in_sizes[2];
    int E = in_sizes[1] / 2;
    float* out = (float*)d_out;

    char* ws = (char*)d_ws;
    size_t off = 0;
    auto take = [&](size_t bytes) {
        void* p = ws + off;
        off = (off + bytes + 255) & ~(size_t)255;
        return p;
    };
    float* bufA = (float*)take((size_t)N * H * 4);
    float* bufB = (float*)take((size_t)N * H * 4);
    int* deg = (int*)take((size_t)N * 4);        // also reused as scatter cursor
    int* offs = (int*)take((size_t)(N + 1) * 4);
    int* csr = (int*)take((size_t)E * 4);
    int* bsum = (int*)take(4096);
    int* boff = (int*)take(4096);
    float* gsum = (float*)take((size_t)NGRAPHS * H * 4);
    float* g = (float*)take((size_t)NGRAPHS * H * 4);
    int* starts = (int*)take((size_t)(NGRAPHS + 1) * 4);

    int nb = (N + 255) / 256;      // 196 (must be <= 256 for single-block scan)
    int eb = (E + 255) / 256;
    int gemmb = (N + TILE_R - 1) / TILE_R;
    int aggb = (N + AGG_NODES - 1) / AGG_NODES;
    int poolb = (N + POOL_ROWS - 1) / POOL_ROWS;

    // CSR build
    hipLaunchKernelGGL(zero_int, dim3(nb), dim3(256), 0, stream, deg, N);
    hipLaunchKernelGGL(count_deg, dim3(eb), dim3(256), 0, stream, ei, deg, E);
    hipLaunchKernelGGL(block_sums, dim3(nb), dim3(256), 0, stream, deg, bsum, N);
    hipLaunchKernelGGL(scan_bsums, dim3(1), dim3(256), 0, stream, bsum, boff, nb);
    hipLaunchKernelGGL(scan_final, dim3(nb), dim3(256), 0, stream, deg, boff, offs, N);
    hipLaunchKernelGGL(zero_int, dim3(nb), dim3(256), 0, stream, deg, N);
    hipLaunchKernelGGL(scatter_edges, dim3(eb), dim3(256), 0, stream, ei, offs, deg, csr, E);

    // layer 1
    hipLaunchKernelGGL(agg_kernel2, dim3(aggb), dim3(256), 0, stream, x, bufA, offs, csr, N);
    hipLaunchKernelGGL(gemm128_bias_relu, dim3(gemmb), dim3(256), 0, stream, bufA, w11, b11, bufB, N);
    hipLaunchKernelGGL(gemm128_bias_relu, dim3(gemmb), dim3(256), 0, stream, bufB, w12, b12, bufA, N);
    // layer 2
    hipLaunchKernelGGL(agg_kernel2, dim3(aggb), dim3(256), 0, stream, bufA, bufB, offs, csr, N);
    hipLaunchKernelGGL(gemm128_bias_relu, dim3(gemmb), dim3(256), 0, stream, bufB, w21, b21, bufA, N);
    hipLaunchKernelGGL(gemm128_bias_relu, dim3(gemmb), dim3(256), 0, stream, bufA, w22, b22, bufB, N);

    // pool + heads
    hipLaunchKernelGGL(find_starts, dim3(1), dim3(256), 0, stream, batch, starts, N, NGRAPHS);
    hipLaunchKernelGGL(zero_float, dim3((NGRAPHS * H + 255) / 256), dim3(256), 0, stream,
                       gsum, NGRAPHS * H);
    hipLaunchKernelGGL(pool_partial, dim3(poolb), dim3(128), 0, stream, bufB, batch, gsum, N);
    hipLaunchKernelGGL(pool_finalize, dim3(NGRAPHS), dim3(128), 0, stream, gsum, starts, g);
    hipLaunchKernelGGL(head_kernel, dim3(NGRAPHS), dim3(128), 0, stream, g,
                       wv1, bv1, wv2, bv2, wa1, ba1, wa2, ba2, out);
}

// Round 4
// 259.716 us; speedup vs baseline: 1.7877x; 1.3563x over previous
//
#include <hip/hip_runtime.h>

#define H 128
#define NGRAPHS 128
#define NADV 32

typedef __attribute__((ext_vector_type(8))) short s8v;   // 8 bf16 (4 VGPR)
typedef __attribute__((ext_vector_type(4))) float f4v;   // MFMA acc

// bf16 helpers (RNE)
__device__ __forceinline__ unsigned short f2bf(float f) {
    unsigned int u = __float_as_uint(f);
    unsigned int r = (u + 0x7fff + ((u >> 16) & 1)) >> 16;
    return (unsigned short)r;
}
__device__ __forceinline__ float bflo(unsigned int u) { return __uint_as_float(u << 16); }
__device__ __forceinline__ float bfhi(unsigned int u) { return __uint_as_float(u & 0xffff0000u); }

// ---------------------------------------------------------------- utilities

__global__ void zero_int(int* __restrict__ p, int n) {
    int i = blockIdx.x * blockDim.x + threadIdx.x;
    if (i < n) p[i] = 0;
}

__global__ void zero_float(float* __restrict__ p, int n) {
    int i = blockIdx.x * blockDim.x + threadIdx.x;
    if (i < n) p[i] = 0.f;
}

__global__ void conv_f32_bf16(const float4* __restrict__ in, ushort4* __restrict__ out, int n4) {
    int i = blockIdx.x * blockDim.x + threadIdx.x;
    if (i < n4) {
        float4 v = in[i];
        ushort4 o;
        o.x = f2bf(v.x); o.y = f2bf(v.y); o.z = f2bf(v.z); o.w = f2bf(v.w);
        out[i] = o;
    }
}

// Pack W [128][128] f32 row-major -> bf16 MFMA B-fragment order.
// frag(kc,ct): lane l, reg r holds W[kc*32 + (l>>4)*8 + r][ct*16 + (l&15)]
__global__ __launch_bounds__(256) void pack_w(const float* __restrict__ W,
                                              unsigned short* __restrict__ wp) {
    int idx = blockIdx.x * 256 + threadIdx.x;   // 0..2047 = (kc,ct,lane)
    int lane = idx & 63;
    int ct = (idx >> 6) & 7;
    int kc = idx >> 9;
    int col = ct * 16 + (lane & 15);
    int kb = kc * 32 + ((lane >> 4) << 3);
    ushort4 lo, hi;
    lo.x = f2bf(W[(kb + 0) * H + col]);
    lo.y = f2bf(W[(kb + 1) * H + col]);
    lo.z = f2bf(W[(kb + 2) * H + col]);
    lo.w = f2bf(W[(kb + 3) * H + col]);
    hi.x = f2bf(W[(kb + 4) * H + col]);
    hi.y = f2bf(W[(kb + 5) * H + col]);
    hi.z = f2bf(W[(kb + 6) * H + col]);
    hi.w = f2bf(W[(kb + 7) * H + col]);
    ((ushort4*)wp)[idx * 2] = lo;
    ((ushort4*)wp)[idx * 2 + 1] = hi;
}

// ---------------------------------------------------------------- CSR build

__global__ void count_deg(const int* __restrict__ ei, int* __restrict__ deg, int E) {
    int e = blockIdx.x * blockDim.x + threadIdx.x;
    if (e < E) atomicAdd(&deg[ei[E + e]], 1);   // dst = edge_index[1][e]
}

__device__ __forceinline__ int wave_incl_scan(int v) {
    int lane = threadIdx.x & 63;
#pragma unroll
    for (int off = 1; off < 64; off <<= 1) {
        int t = __shfl_up(v, off);
        if (lane >= off) v += t;
    }
    return v;
}

__device__ __forceinline__ int block_incl_scan_256(int v, int* wsum) {
    int incl = wave_incl_scan(v);
    int wid = threadIdx.x >> 6;
    if ((threadIdx.x & 63) == 63) wsum[wid] = incl;
    __syncthreads();
    int prefix = 0;
#pragma unroll
    for (int w = 0; w < 4; ++w)
        if (w < wid) prefix += wsum[w];
    return incl + prefix;
}

__global__ __launch_bounds__(256) void block_sums(const int* __restrict__ deg,
                                                  int* __restrict__ bsum, int n) {
    __shared__ int wsum[4];
    int i = blockIdx.x * 256 + threadIdx.x;
    int s = (i < n) ? deg[i] : 0;
#pragma unroll
    for (int off = 32; off > 0; off >>= 1) s += __shfl_down(s, off);
    if ((threadIdx.x & 63) == 0) wsum[threadIdx.x >> 6] = s;
    __syncthreads();
    if (threadIdx.x == 0) bsum[blockIdx.x] = wsum[0] + wsum[1] + wsum[2] + wsum[3];
}

__global__ __launch_bounds__(256) void scan_bsums(const int* __restrict__ bsum,
                                                  int* __restrict__ boff, int nb) {
    __shared__ int wsum[4];
    int v = (threadIdx.x < nb) ? bsum[threadIdx.x] : 0;
    int incl = block_incl_scan_256(v, wsum);
    if (threadIdx.x < nb) boff[threadIdx.x] = incl - v;  // exclusive
}

__global__ __launch_bounds__(256) void scan_final(const int* __restrict__ deg,
                                                  const int* __restrict__ boff,
                                                  int* __restrict__ offs, int n) {
    __shared__ int wsum[4];
    int i = blockIdx.x * 256 + threadIdx.x;
    int v = (i < n) ? deg[i] : 0;
    int incl = block_incl_scan_256(v, wsum);
    if (i < n) offs[i + 1] = boff[blockIdx.x] + incl;
    if (i == 0) offs[0] = 0;
}

__global__ void scatter_edges(const int* __restrict__ ei, const int* __restrict__ offs,
                              int* __restrict__ cursor, int* __restrict__ csr, int E) {
    int e = blockIdx.x * blockDim.x + threadIdx.x;
    if (e < E) {
        int dst = ei[E + e];
        int src = ei[e];
        int pos = offs[dst] + atomicAdd(&cursor[dst], 1);
        csr[pos] = src;
    }
}

// ------------------------------------------------------------- aggregation
// bf16 in/out, fp32 accumulate. 8 nodes/block, 32 lanes/node, 8B (4 bf16)/lane.
constexpr int AGG_NODES = 8;

__global__ __launch_bounds__(256) void agg_bf16(const uint2* __restrict__ in,
                                                uint2* __restrict__ out,
                                                const int* __restrict__ offs,
                                                const int* __restrict__ csr, int n) {
    int t = threadIdx.x;
    int lane = t & 31;
    int node = blockIdx.x * AGG_NODES + (t >> 5);
    if (node >= n) return;
    int beg = offs[node], end = offs[node + 1];
    uint2 s = in[(size_t)node * 32 + lane];
    float a0 = bflo(s.x), a1 = bfhi(s.x), a2 = bflo(s.y), a3 = bfhi(s.y);
    for (int e0 = beg; e0 < end; e0 += 32) {
        int cnt = min(32, end - e0);
        int my = (lane < cnt) ? csr[e0 + lane] : 0;
        for (int j = 0; j < cnt; ++j) {
            int src = __shfl(my, j, 32);
            uint2 v = in[(size_t)src * 32 + lane];
            a0 += bflo(v.x); a1 += bfhi(v.x);
            a2 += bflo(v.y); a3 += bfhi(v.y);
        }
    }
    uint2 o;
    o.x = (unsigned int)f2bf(a0) | ((unsigned int)f2bf(a1) << 16);
    o.y = (unsigned int)f2bf(a2) | ((unsigned int)f2bf(a3) << 16);
    out[(size_t)node * 32 + lane] = o;
}

// ------------------------------------------------------------------- GEMM
// out[r][c] = relu( sum_k in[r][k]*W[k][c] + b[c] )
// in: [n,128] bf16 row-major; wp: packed B-frags; out: [n,128] bf16.
// 256 thr = 4 waves; 64 rows/block (16 rows/wave), full 128 cols, no LDS.
__global__ __launch_bounds__(256) void gemm_mfma_bf16(const unsigned short* __restrict__ in,
                                                      const s8v* __restrict__ wp,
                                                      const float* __restrict__ bias,
                                                      unsigned short* __restrict__ out, int n) {
    int tid = threadIdx.x;
    int w = tid >> 6;
    int l = tid & 63;
    int r0 = blockIdx.x * 64 + w * 16;
    int arow = r0 + (l & 15);
    int arowc = min(arow, n - 1);
    int acol = (l >> 4) << 3;          // 0,8,16,24 within 32-wide k-chunk

    s8v a[4];
#pragma unroll
    for (int kc = 0; kc < 4; ++kc)
        a[kc] = *(const s8v*)(in + (size_t)arowc * H + kc * 32 + acol);

    f4v acc[8];
#pragma unroll
    for (int ct = 0; ct < 8; ++ct) acc[ct] = (f4v){0.f, 0.f, 0.f, 0.f};

#pragma unroll
    for (int ct = 0; ct < 8; ++ct)
#pragma unroll
        for (int kc = 0; kc < 4; ++kc)
            acc[ct] = __builtin_amdgcn_mfma_f32_16x16x32_bf16(
                a[kc], wp[(kc * 8 + ct) * 64 + l], acc[ct], 0, 0, 0);

    int crow = (l >> 4) << 2;          // C row base within 16x16 tile
    int ccol = l & 15;
#pragma unroll
    for (int ct = 0; ct < 8; ++ct) {
        int col = ct * 16 + ccol;
        float bv = bias[col];
#pragma unroll
        for (int rr = 0; rr < 4; ++rr) {
            int row = r0 + crow + rr;
            if (row < n) {
                float v = fmaxf(acc[ct][rr] + bv, 0.f);
                out[(size_t)row * H + col] = f2bf(v);
            }
        }
    }
}

// ------------------------------------------------------------------- pool

__global__ void find_starts(const int* __restrict__ batch, int* __restrict__ starts,
                            int n, int ngraphs) {
    int g = blockIdx.x * blockDim.x + threadIdx.x;
    if (g > ngraphs) return;
    int lo = 0, hi = n;
    while (lo < hi) {
        int mid = (lo + hi) >> 1;
        if (batch[mid] < g) lo = mid + 1;
        else hi = mid;
    }
    starts[g] = lo;
}

constexpr int POOL_ROWS = 128;

__global__ __launch_bounds__(128) void pool_partial(const unsigned short* __restrict__ h,
                                                    const int* __restrict__ batch,
                                                    float* __restrict__ sums, int n) {
    __shared__ int bseg[POOL_ROWS];
    int r0 = blockIdx.x * POOL_ROWS;
    int r1 = min(r0 + POOL_ROWS, n);
    int nrows = r1 - r0;
    int c = threadIdx.x;
    if (c < nrows) bseg[c] = batch[r0 + c];
    __syncthreads();
    if (nrows <= 0) return;
    int g = bseg[0];
    float s = 0.f;
    for (int i = 0; i < nrows; ++i) {
        int bg = bseg[i];
        if (bg != g) {
            atomicAdd(&sums[g * H + c], s);
            s = 0.f;
            g = bg;
        }
        s += __uint_as_float(((unsigned int)h[(size_t)(r0 + i) * H + c]) << 16);
    }
    atomicAdd(&sums[g * H + c], s);
}

__global__ __launch_bounds__(128) void pool_finalize(const float* __restrict__ sums,
                                                     const int* __restrict__ starts,
                                                     float* __restrict__ g) {
    int gi = blockIdx.x;
    int c = threadIdx.x;
    float cnt = (float)(starts[gi + 1] - starts[gi]);
    g[gi * H + c] = sums[gi * H + c] / fmaxf(cnt, 1.0f);
}

// ------------------------------------------------------------------- head

__global__ __launch_bounds__(128) void head_kernel(const float* __restrict__ g,
                                                   const float* __restrict__ wv1,
                                                   const float* __restrict__ bv1,
                                                   const float* __restrict__ wv2,
                                                   const float* __restrict__ bv2,
                                                   const float* __restrict__ wa1,
                                                   const float* __restrict__ ba1,
                                                   const float* __restrict__ wa2,
                                                   const float* __restrict__ ba2,
                                                   float* __restrict__ out) {
    __shared__ float row[H];
    __shared__ float hv[H];
    __shared__ float ha[H];
    __shared__ float adv[NADV];
    __shared__ float vred[2];
    int gi = blockIdx.x;
    int c = threadIdx.x;
    row[c] = g[gi * H + c];
    __syncthreads();
    float sv = bv1[c], sa = ba1[c];
    for (int k = 0; k < H; ++k) {
        float rk = row[k];
        sv += rk * wv1[k * H + c];
        sa += rk * wa1[k * H + c];
    }
    hv[c] = fmaxf(sv, 0.f);
    ha[c] = fmaxf(sa, 0.f);
    __syncthreads();
    float p = hv[c] * wv2[c];
#pragma unroll
    for (int off = 32; off > 0; off >>= 1) p += __shfl_down(p, off);
    if ((c & 63) == 0) vred[c >> 6] = p;
    __syncthreads();
    float value = vred[0] + vred[1] + bv2[0];
    if (c < NADV) {
        float s = ba2[c];
        for (int k = 0; k < H; ++k) s += ha[k] * wa2[k * NADV + c];
        adv[c] = s;
    }
    __syncthreads();
    if (c < NADV) {
        float m = 0.f;
#pragma unroll
        for (int j = 0; j < NADV; ++j) m += adv[j];
        m *= (1.0f / NADV);
        out[gi * NADV + c] = value + adv[c] - m;
    }
}

// ----------------------------------------------------------------- launch

extern "C" void kernel_launch(void* const* d_in, const int* in_sizes, int n_in,
                              void* d_out, int out_size, void* d_ws, size_t ws_size,
                              hipStream_t stream) {
    const float* x = (const float*)d_in[0];
    const int* ei = (const int*)d_in[1];
    const int* batch = (const int*)d_in[2];
    const float* w11 = (const float*)d_in[3];
    const float* b11 = (const float*)d_in[4];
    const float* w12 = (const float*)d_in[5];
    const float* b12 = (const float*)d_in[6];
    const float* w21 = (const float*)d_in[7];
    const float* b21 = (const float*)d_in[8];
    const float* w22 = (const float*)d_in[9];
    const float* b22 = (const float*)d_in[10];
    const float* wv1 = (const float*)d_in[11];
    const float* bv1 = (const float*)d_in[12];
    const float* wv2 = (const float*)d_in[13];
    const float* bv2 = (const float*)d_in[14];
    const float* wa1 = (const float*)d_in[15];
    const float* ba1 = (const float*)d_in[16];
    const float* wa2 = (const float*)d_in[17];
    const float* ba2 = (const float*)d_in[18];

    int N = in_sizes[2];
    int E = in_sizes[1] / 2;
    float* out = (float*)d_out;

    char* ws = (char*)d_ws;
    size_t off = 0;
    auto take = [&](size_t bytes) {
        void* p = ws + off;
        off = (off + bytes + 255) & ~(size_t)255;
        return p;
    };
    unsigned short* xb = (unsigned short*)take((size_t)N * H * 2);
    unsigned short* u1 = (unsigned short*)take((size_t)N * H * 2);
    unsigned short* u2 = (unsigned short*)take((size_t)N * H * 2);
    unsigned short* wp1 = (unsigned short*)take(H * H * 2);
    unsigned short* wp2 = (unsigned short*)take(H * H * 2);
    unsigned short* wp3 = (unsigned short*)take(H * H * 2);
    unsigned short* wp4 = (unsigned short*)take(H * H * 2);
    int* deg = (int*)take((size_t)N * 4);
    int* offs = (int*)take((size_t)(N + 1) * 4);
    int* csr = (int*)take((size_t)E * 4);
    int* bsum = (int*)take(4096);
    int* boff = (int*)take(4096);
    float* gsum = (float*)take((size_t)NGRAPHS * H * 4);
    float* g = (float*)take((size_t)NGRAPHS * H * 4);
    int* starts = (int*)take((size_t)(NGRAPHS + 1) * 4);

    int nb = (N + 255) / 256;
    int eb = (E + 255) / 256;
    int gemmb = (N + 63) / 64;
    int aggb = (N + AGG_NODES - 1) / AGG_NODES;
    int poolb = (N + POOL_ROWS - 1) / POOL_ROWS;
    int cvb = (N * H / 4 + 255) / 256;

    // convert inputs to bf16 / packed
    hipLaunchKernelGGL(conv_f32_bf16, dim3(cvb), dim3(256), 0, stream,
                       (const float4*)x, (ushort4*)xb, N * H / 4);
    hipLaunchKernelGGL(pack_w, dim3(8), dim3(256), 0, stream, w11, wp1);
    hipLaunchKernelGGL(pack_w, dim3(8), dim3(256), 0, stream, w12, wp2);
    hipLaunchKernelGGL(pack_w, dim3(8), dim3(256), 0, stream, w21, wp3);
    hipLaunchKernelGGL(pack_w, dim3(8), dim3(256), 0, stream, w22, wp4);

    // CSR build
    hipLaunchKernelGGL(zero_int, dim3(nb), dim3(256), 0, stream, deg, N);
    hipLaunchKernelGGL(count_deg, dim3(eb), dim3(256), 0, stream, ei, deg, E);
    hipLaunchKernelGGL(block_sums, dim3(nb), dim3(256), 0, stream, deg, bsum, N);
    hipLaunchKernelGGL(scan_bsums, dim3(1), dim3(256), 0, stream, bsum, boff, nb);
    hipLaunchKernelGGL(scan_final, dim3(nb), dim3(256), 0, stream, deg, boff, offs, N);
    hipLaunchKernelGGL(zero_int, dim3(nb), dim3(256), 0, stream, deg, N);
    hipLaunchKernelGGL(scatter_edges, dim3(eb), dim3(256), 0, stream, ei, offs, deg, csr, E);

    // layer 1
    hipLaunchKernelGGL(agg_bf16, dim3(aggb), dim3(256), 0, stream,
                       (const uint2*)xb, (uint2*)u1, offs, csr, N);
    hipLaunchKernelGGL(gemm_mfma_bf16, dim3(gemmb), dim3(256), 0, stream,
                       u1, (const s8v*)wp1, b11, u2, N);
    hipLaunchKernelGGL(gemm_mfma_bf16, dim3(gemmb), dim3(256), 0, stream,
                       u2, (const s8v*)wp2, b12, u1, N);
    // layer 2
    hipLaunchKernelGGL(agg_bf16, dim3(aggb), dim3(256), 0, stream,
                       (const uint2*)u1, (uint2*)u2, offs, csr, N);
    hipLaunchKernelGGL(gemm_mfma_bf16, dim3(gemmb), dim3(256), 0, stream,
                       u2, (const s8v*)wp3, b21, u1, N);
    hipLaunchKernelGGL(gemm_mfma_bf16, dim3(gemmb), dim3(256), 0, stream,
                       u1, (const s8v*)wp4, b22, u2, N);

    // pool + heads
    hipLaunchKernelGGL(find_starts, dim3(1), dim3(256), 0, stream, batch, starts, N, NGRAPHS);
    hipLaunchKernelGGL(zero_float, dim3((NGRAPHS * H + 255) / 256), dim3(256), 0, stream,
                       gsum, NGRAPHS * H);
    hipLaunchKernelGGL(pool_partial, dim3(poolb), dim3(128), 0, stream, u2, batch, gsum, N);
    hipLaunchKernelGGL(pool_finalize, dim3(NGRAPHS), dim3(128), 0, stream, gsum, starts, g);
    hipLaunchKernelGGL(head_kernel, dim3(NGRAPHS), dim3(128), 0, stream, g,
                       wv1, bv1, wv2, bv2, wa1, ba1, wa2, ba2, out);
}

// Round 6
// 214.582 us; speedup vs baseline: 2.1637x; 1.2103x over previous
//
#include <hip/hip_runtime.h>

#define H 128
#define NGRAPHS 128
#define NADV 32

constexpr int ROWS = 64;    // rows per fused-layer block
constexpr int LSTR = 136;   // LDS row stride in bf16 elements (272B, 16B-aligned, low conflict)

typedef __attribute__((ext_vector_type(8))) short s8v;   // 8 bf16
typedef __attribute__((ext_vector_type(4))) float f4v;   // MFMA acc

// bf16 helpers (RNE)
__device__ __forceinline__ unsigned short f2bf(float f) {
    unsigned int u = __float_as_uint(f);
    unsigned int r = (u + 0x7fff + ((u >> 16) & 1)) >> 16;
    return (unsigned short)r;
}
__device__ __forceinline__ float bflo(unsigned int u) { return __uint_as_float(u << 16); }
__device__ __forceinline__ float bfhi(unsigned int u) { return __uint_as_float(u & 0xffff0000u); }

// ---------------------------------------------------------------- utilities

__global__ void zero_int(int* __restrict__ p, int n) {
    int i = blockIdx.x * blockDim.x + threadIdx.x;
    if (i < n) p[i] = 0;
}

__global__ void conv_f32_bf16(const float4* __restrict__ in, ushort4* __restrict__ out, int n4) {
    int i = blockIdx.x * blockDim.x + threadIdx.x;
    if (i < n4) {
        float4 v = in[i];
        ushort4 o;
        o.x = f2bf(v.x); o.y = f2bf(v.y); o.z = f2bf(v.z); o.w = f2bf(v.w);
        out[i] = o;
    }
}

// Pack all four W [128][128] f32 row-major -> bf16 MFMA B-fragment order.
// frag(kc,ct): lane l, reg r holds W[kc*32 + (l>>4)*8 + r][ct*16 + (l&15)]
__global__ __launch_bounds__(256) void pack_all(const float* __restrict__ W0,
                                                const float* __restrict__ W1,
                                                const float* __restrict__ W2,
                                                const float* __restrict__ W3,
                                                unsigned short* __restrict__ P0,
                                                unsigned short* __restrict__ P1,
                                                unsigned short* __restrict__ P2,
                                                unsigned short* __restrict__ P3) {
    int idx = blockIdx.x * 256 + threadIdx.x;   // 0..8191
    int wsel = idx >> 11;
    const float* W = (wsel == 0) ? W0 : (wsel == 1) ? W1 : (wsel == 2) ? W2 : W3;
    unsigned short* P = (wsel == 0) ? P0 : (wsel == 1) ? P1 : (wsel == 2) ? P2 : P3;
    int id = idx & 2047;                        // (kc,ct,lane)
    int lane = id & 63;
    int ct = (id >> 6) & 7;
    int kc = id >> 9;
    int col = ct * 16 + (lane & 15);
    int kb = kc * 32 + ((lane >> 4) << 3);
    ushort4 lo, hi;
    lo.x = f2bf(W[(kb + 0) * H + col]);
    lo.y = f2bf(W[(kb + 1) * H + col]);
    lo.z = f2bf(W[(kb + 2) * H + col]);
    lo.w = f2bf(W[(kb + 3) * H + col]);
    hi.x = f2bf(W[(kb + 4) * H + col]);
    hi.y = f2bf(W[(kb + 5) * H + col]);
    hi.z = f2bf(W[(kb + 6) * H + col]);
    hi.w = f2bf(W[(kb + 7) * H + col]);
    ((ushort4*)P)[id * 2] = lo;
    ((ushort4*)P)[id * 2 + 1] = hi;
}

// ---------------------------------------------------------------- CSR build

__global__ void count_deg(const int* __restrict__ ei, int* __restrict__ deg, int E) {
    int e = blockIdx.x * blockDim.x + threadIdx.x;
    if (e < E) atomicAdd(&deg[ei[E + e]], 1);   // dst = edge_index[1][e]
}

__device__ __forceinline__ int wave_incl_scan(int v) {
    int lane = threadIdx.x & 63;
#pragma unroll
    for (int off = 1; off < 64; off <<= 1) {
        int t = __shfl_up(v, off);
        if (lane >= off) v += t;
    }
    return v;
}

__device__ __forceinline__ int block_incl_scan_256(int v, int* wsum) {
    int incl = wave_incl_scan(v);
    int wid = threadIdx.x >> 6;
    if ((threadIdx.x & 63) == 63) wsum[wid] = incl;
    __syncthreads();
    int prefix = 0;
#pragma unroll
    for (int w = 0; w < 4; ++w)
        if (w < wid) prefix += wsum[w];
    return incl + prefix;
}

__global__ __launch_bounds__(256) void block_sums(const int* __restrict__ deg,
                                                  int* __restrict__ bsum, int n) {
    __shared__ int wsum[4];
    int i = blockIdx.x * 256 + threadIdx.x;
    int s = (i < n) ? deg[i] : 0;
#pragma unroll
    for (int off = 32; off > 0; off >>= 1) s += __shfl_down(s, off);
    if ((threadIdx.x & 63) == 0) wsum[threadIdx.x >> 6] = s;
    __syncthreads();
    if (threadIdx.x == 0) bsum[blockIdx.x] = wsum[0] + wsum[1] + wsum[2] + wsum[3];
}

__global__ __launch_bounds__(256) void scan_bsums(const int* __restrict__ bsum,
                                                  int* __restrict__ boff, int nb) {
    __shared__ int wsum[4];
    int v = (threadIdx.x < nb) ? bsum[threadIdx.x] : 0;
    int incl = block_incl_scan_256(v, wsum);
    if (threadIdx.x < nb) boff[threadIdx.x] = incl - v;  // exclusive
}

__global__ __launch_bounds__(256) void scan_final(const int* __restrict__ deg,
                                                  const int* __restrict__ boff,
                                                  int* __restrict__ offs, int n) {
    __shared__ int wsum[4];
    int i = blockIdx.x * 256 + threadIdx.x;
    int v = (i < n) ? deg[i] : 0;
    int incl = block_incl_scan_256(v, wsum);
    if (i < n) offs[i + 1] = boff[blockIdx.x] + incl;
    if (i == 0) offs[0] = 0;
}

__global__ void scatter_edges(const int* __restrict__ ei, const int* __restrict__ offs,
                              int* __restrict__ cursor, int* __restrict__ csr, int E) {
    int e = blockIdx.x * blockDim.x + threadIdx.x;
    if (e < E) {
        int dst = ei[E + e];
        int src = ei[e];
        int pos = offs[dst] + atomicAdd(&cursor[dst], 1);
        csr[pos] = src;
    }
}

// ------------------------------------------------------- fused GIN layer
// phase1: agg (gather+self) -> LDS As (bf16)
// phase2: GEMM1 relu -> LDS Bs
// phase3: GEMM2 relu -> LDS As
// MODE 0: write As rows to hout (bf16); blocks<64 also zero gsum for next layer
// MODE 1: pool As rows into gsum via per-block run reduction + atomicAdd

__device__ __forceinline__ void gemm_stage(const unsigned short* S, const s8v* __restrict__ wp,
                                           const float* __restrict__ bias, unsigned short* D) {
    int tid = threadIdx.x;
    int w = tid >> 6;
    int l = tid & 63;
    int arow = w * 16 + (l & 15);
    int acol = (l >> 4) << 3;
    s8v a[4];
#pragma unroll
    for (int kc = 0; kc < 4; ++kc)
        a[kc] = *(const s8v*)(S + arow * LSTR + kc * 32 + acol);
    f4v acc[8];
#pragma unroll
    for (int ct = 0; ct < 8; ++ct) acc[ct] = (f4v){0.f, 0.f, 0.f, 0.f};
#pragma unroll
    for (int ct = 0; ct < 8; ++ct)
#pragma unroll
        for (int kc = 0; kc < 4; ++kc)
            acc[ct] = __builtin_amdgcn_mfma_f32_16x16x32_bf16(
                a[kc], wp[(kc * 8 + ct) * 64 + l], acc[ct], 0, 0, 0);
    int crow = w * 16 + ((l >> 4) << 2);
    int ccol = l & 15;
#pragma unroll
    for (int ct = 0; ct < 8; ++ct) {
        int col = ct * 16 + ccol;
        float bv = bias[col];
#pragma unroll
        for (int rr = 0; rr < 4; ++rr) {
            float v = fmaxf(acc[ct][rr] + bv, 0.f);
            D[(crow + rr) * LSTR + col] = f2bf(v);
        }
    }
}

template <int MODE>
__global__ __launch_bounds__(256) void layer_fused(const uint2* __restrict__ in,
                                                   const int* __restrict__ offs,
                                                   const int* __restrict__ csr,
                                                   const s8v* __restrict__ wpA,
                                                   const float* __restrict__ biasA,
                                                   const s8v* __restrict__ wpB,
                                                   const float* __restrict__ biasB,
                                                   unsigned short* __restrict__ hout,
                                                   float* __restrict__ gsum,
                                                   const int* __restrict__ batch, int n) {
    __shared__ unsigned short As[ROWS * LSTR];
    __shared__ unsigned short Bs[ROWS * LSTR];
    __shared__ int bseg[ROWS];
    int tid = threadIdx.x;
    int row0 = blockIdx.x * ROWS;

    if (MODE == 0) {
        if (blockIdx.x < 64) gsum[blockIdx.x * 256 + tid] = 0.f;   // zero for layer-2 pool
    } else {
        if (tid < ROWS) bseg[tid] = (row0 + tid < n) ? batch[row0 + tid] : -1;
    }

    // ---- phase 1: aggregation
    {
        int gidx = tid >> 5, lane = tid & 31;
        for (int i = 0; i < 8; ++i) {
            int local = gidx * 8 + i;
            int node = row0 + local;
            unsigned int ox = 0, oy = 0;
            if (node < n) {
                int beg = offs[node], end = offs[node + 1];
                uint2 s = in[(size_t)node * 32 + lane];
                float a0 = bflo(s.x), a1 = bfhi(s.x), a2 = bflo(s.y), a3 = bfhi(s.y);
                for (int e0 = beg; e0 < end; e0 += 32) {
                    int cnt = min(32, end - e0);
                    int my = (lane < cnt) ? csr[e0 + lane] : 0;
                    for (int j = 0; j < cnt; ++j) {
                        int src = __shfl(my, j, 32);
                        uint2 v = in[(size_t)src * 32 + lane];
                        a0 += bflo(v.x); a1 += bfhi(v.x);
                        a2 += bflo(v.y); a3 += bfhi(v.y);
                    }
                }
                ox = (unsigned int)f2bf(a0) | ((unsigned int)f2bf(a1) << 16);
                oy = (unsigned int)f2bf(a2) | ((unsigned int)f2bf(a3) << 16);
            }
            *(uint2*)(&As[local * LSTR + lane * 4]) = make_uint2(ox, oy);
        }
    }
    __syncthreads();
    // ---- phase 2: GEMM1 (relu)
    gemm_stage(As, wpA, biasA, Bs);
    __syncthreads();
    // ---- phase 3: GEMM2 (relu)
    gemm_stage(Bs, wpB, biasB, As);
    __syncthreads();

    if (MODE == 0) {
        // write h rows to global, vectorized
        int r = tid >> 2, cseg = tid & 3;
        int row = row0 + r;
        if (row < n) {
#pragma unroll
            for (int q = 0; q < 4; ++q) {
                uint4 v = *(const uint4*)(&As[r * LSTR + cseg * 32 + q * 8]);
                *(uint4*)(&hout[(size_t)row * H + cseg * 32 + q * 8]) = v;
            }
        }
    } else {
        // pool: run-reduce 32 rows per half, flush per graph run
        int half = tid >> 7, c = tid & 127;
        int rbeg = half * 32, rend = rbeg + 32;
        int g = bseg[rbeg];
        float s = 0.f;
        for (int r = rbeg; r < rend; ++r) {
            int bg = bseg[r];
            if (bg != g) {
                if (g >= 0) atomicAdd(&gsum[g * H + c], s);
                s = 0.f;
                g = bg;
            }
            s += __uint_as_float(((unsigned int)As[r * LSTR + c]) << 16);
        }
        if (g >= 0) atomicAdd(&gsum[g * H + c], s);
    }
}

// ------------------------------------------------------------------- head
// integrates: graph-boundary search, mean finalize, both MLP heads

__global__ __launch_bounds__(128) void head_kernel(const float* __restrict__ gsum,
                                                   const int* __restrict__ batch, int n,
                                                   const float* __restrict__ wv1,
                                                   const float* __restrict__ bv1,
                                                   const float* __restrict__ wv2,
                                                   const float* __restrict__ bv2,
                                                   const float* __restrict__ wa1,
                                                   const float* __restrict__ ba1,
                                                   const float* __restrict__ wa2,
                                                   const float* __restrict__ ba2,
                                                   float* __restrict__ out) {
    __shared__ float row[H];
    __shared__ float hv[H];
    __shared__ float ha[H];
    __shared__ float adv[NADV];
    __shared__ float vred[2];
    __shared__ int se[2];
    int gi = blockIdx.x;
    int c = threadIdx.x;
    if (c < 2) {
        int target = gi + c;
        int lo = 0, hi = n;
        while (lo < hi) {
            int mid = (lo + hi) >> 1;
            if (batch[mid] < target) lo = mid + 1;
            else hi = mid;
        }
        se[c] = lo;
    }
    __syncthreads();
    float cnt = (float)(se[1] - se[0]);
    row[c] = gsum[gi * H + c] / fmaxf(cnt, 1.0f);
    __syncthreads();
    float sv = bv1[c], sa = ba1[c];
    for (int k = 0; k < H; ++k) {
        float rk = row[k];
        sv += rk * wv1[k * H + c];
        sa += rk * wa1[k * H + c];
    }
    hv[c] = fmaxf(sv, 0.f);
    ha[c] = fmaxf(sa, 0.f);
    __syncthreads();
    float p = hv[c] * wv2[c];
#pragma unroll
    for (int off = 32; off > 0; off >>= 1) p += __shfl_down(p, off);
    if ((c & 63) == 0) vred[c >> 6] = p;
    __syncthreads();
    float value = vred[0] + vred[1] + bv2[0];
    if (c < NADV) {
        float s = ba2[c];
        for (int k = 0; k < H; ++k) s += ha[k] * wa2[k * NADV + c];
        adv[c] = s;
    }
    __syncthreads();
    if (c < NADV) {
        float m = 0.f;
#pragma unroll
        for (int j = 0; j < NADV; ++j) m += adv[j];
        m *= (1.0f / NADV);
        out[gi * NADV + c] = value + adv[c] - m;
    }
}

// ----------------------------------------------------------------- launch

extern "C" void kernel_launch(void* const* d_in, const int* in_sizes, int n_in,
                              void* d_out, int out_size, void* d_ws, size_t ws_size,
                              hipStream_t stream) {
    const float* x = (const float*)d_in[0];
    const int* ei = (const int*)d_in[1];
    const int* batch = (const int*)d_in[2];
    const float* w11 = (const float*)d_in[3];
    const float* b11 = (const float*)d_in[4];
    const float* w12 = (const float*)d_in[5];
    const float* b12 = (const float*)d_in[6];
    const float* w21 = (const float*)d_in[7];
    const float* b21 = (const float*)d_in[8];
    const float* w22 = (const float*)d_in[9];
    const float* b22 = (const float*)d_in[10];
    const float* wv1 = (const float*)d_in[11];
    const float* bv1 = (const float*)d_in[12];
    const float* wv2 = (const float*)d_in[13];
    const float* bv2 = (const float*)d_in[14];
    const float* wa1 = (const float*)d_in[15];
    const float* ba1 = (const float*)d_in[16];
    const float* wa2 = (const float*)d_in[17];
    const float* ba2 = (const float*)d_in[18];

    int N = in_sizes[2];
    int E = in_sizes[1] / 2;
    float* out = (float*)d_out;

    char* ws = (char*)d_ws;
    size_t off = 0;
    auto take = [&](size_t bytes) {
        void* p = ws + off;
        off = (off + bytes + 255) & ~(size_t)255;
        return p;
    };
    unsigned short* xb = (unsigned short*)take((size_t)N * H * 2);
    unsigned short* u1 = (unsigned short*)take((size_t)N * H * 2);
    unsigned short* wp1 = (unsigned short*)take(H * H * 2);
    unsigned short* wp2 = (unsigned short*)take(H * H * 2);
    unsigned short* wp3 = (unsigned short*)take(H * H * 2);
    unsigned short* wp4 = (unsigned short*)take(H * H * 2);
    // deg and cursor MUST be truly contiguous (one allocation) so a single
    // zero_int(deg, 2*N) covers both — take() rounds sizes up to 256B, so
    // two separate takes would leave a poisoned tail in cursor (round-5 crash).
    int* deg = (int*)take((size_t)2 * N * 4);
    int* cursor = deg + N;
    int* offs = (int*)take((size_t)(N + 1) * 4);
    int* csr = (int*)take((size_t)E * 4);
    int* bsum = (int*)take(4096);
    int* boff = (int*)take(4096);
    float* gsum = (float*)take((size_t)NGRAPHS * H * 4);

    int nb = (N + 255) / 256;            // 196 <= 256 (single-block scan limit)
    int eb = (E + 255) / 256;
    int lb = (N + ROWS - 1) / ROWS;      // 782
    int cvb = (N * H / 4 + 255) / 256;

    // convert + pack
    hipLaunchKernelGGL(conv_f32_bf16, dim3(cvb), dim3(256), 0, stream,
                       (const float4*)x, (ushort4*)xb, N * H / 4);
    hipLaunchKernelGGL(pack_all, dim3(32), dim3(256), 0, stream,
                       w11, w12, w21, w22, wp1, wp2, wp3, wp4);

    // CSR build
    hipLaunchKernelGGL(zero_int, dim3((2 * N + 255) / 256), dim3(256), 0, stream, deg, 2 * N);
    hipLaunchKernelGGL(count_deg, dim3(eb), dim3(256), 0, stream, ei, deg, E);
    hipLaunchKernelGGL(block_sums, dim3(nb), dim3(256), 0, stream, deg, bsum, N);
    hipLaunchKernelGGL(scan_bsums, dim3(1), dim3(256), 0, stream, bsum, boff, nb);
    hipLaunchKernelGGL(scan_final, dim3(nb), dim3(256), 0, stream, deg, boff, offs, N);
    hipLaunchKernelGGL(scatter_edges, dim3(eb), dim3(256), 0, stream, ei, offs, cursor, csr, E);

    // layer 1 (agg + 2 GEMMs) -> u1 ; also zeroes gsum
    hipLaunchKernelGGL((layer_fused<0>), dim3(lb), dim3(256), 0, stream,
                       (const uint2*)xb, offs, csr,
                       (const s8v*)wp1, b11, (const s8v*)wp2, b12,
                       u1, gsum, batch, N);
    // layer 2 (agg + 2 GEMMs + pool) -> gsum
    hipLaunchKernelGGL((layer_fused<1>), dim3(lb), dim3(256), 0, stream,
                       (const uint2*)u1, offs, csr,
                       (const s8v*)wp3, b21, (const s8v*)wp4, b22,
                       (unsigned short*)nullptr, gsum, batch, N);

    // heads (finalize + value/advantage + combine)
    hipLaunchKernelGGL(head_kernel, dim3(NGRAPHS), dim3(128), 0, stream,
                       gsum, batch, N,
                       wv1, bv1, wv2, bv2, wa1, ba1, wa2, ba2, out);
}